// Round 15
// baseline (109.742 us; speedup 1.0000x reference)
//
#include <hip/hip_runtime.h>
#include <math.h>

#define IR_LEN  2000
#define PFRAME  80
#define NFRAMES 300
#define NBATCH  2
#define NROWS   (NBATCH*NFRAMES)     // 600
#define T_TOTAL (NFRAMES*PFRAME)     // 24000
#define NCOEF   25
#define TWO_PI  6.283185307179586f
#define GS      68                   // G row stride in floats
#define XWN     2160                 // logical x-window floats per block
#define XWPAD   2432                 // physical (4-float pad per 32)

#define XPHYS(B) ((B) + (((B) >> 5) << 2))

__device__ __forceinline__ void fsincos(float a, float* s, float* c) {
    *s = __sinf(a); *c = __cosf(a);
}

// ---------------------------------------------------------------------------
// Fully fused kernel: one block per (batch,frame) row. 600 blocks, 256 thr.
// R12 EXACT code shape (proven VGPR 72 / 46 us) + minimal Hermitian deltas:
//   - G'[d][64-b] = conj(G'[d][b]) (validated end-to-end in R13) =>
//     stage 1: threads with (t&15) > 8 are masked off (their b-columns are
//     redundant); store guarded to b <= 32. NO code-shape change otherwise.
//     Masked lanes issue no LDS reads -> stage-1 LDS traffic ~halved.
//   - stage 2: 31 STEP2s + boundary (h = g0 + (-1)^cg g32 + 2*sum), the
//     R13-validated formula, reading the same G layout (rows 0..32).
// Everything else (x-stage, E phase, FIR, epilogue) is R12 verbatim.
// ---------------------------------------------------------------------------
__global__ __launch_bounds__(256) void minphase_fir_fused(
        const float* __restrict__ mc, const float* __restrict__ x,
        float* __restrict__ y) {
    __shared__ __align__(16) float U[8704];    // 34.8 KB union
    __shared__ __align__(16) float xws[XWPAD]; // 9.7 KB padded x window
    __shared__ float csh[NCOEF];
    float* const EHr = U;                      // [4096]      (phase E)
    float* const EHi = U + 4096;               // [4096]
    float* const Gr  = U;                      // [rows b<=32] (stages 1/2)
    float* const Gi  = U + 4352;               // [rows b<=32]
    float* const hU  = U;                      // [2000]      (FIR phase)
    float* const red = U + 4224;               // [12 rows, stride 168]

    const int row   = blockIdx.x;
    const int batch = row / NFRAMES;
    const int frame = row - batch * NFRAMES;
    const int t0    = frame * PFRAME;
    const int t     = threadIdx.x;

    if (t < NCOEF) csh[t] = mc[row * NCOEF + t];

    // ---------------- stage x: pre-stage x window (padded) ----------------
    {
        const float* xb = x + batch * T_TOTAL;
        for (int j = t; j < XWN; j += 256) {
            const int xi = t0 - 2079 + j;
            const float v = (xi >= 0 && xi < T_TOTAL) ? xb[xi] : 0.0f;
            xws[XPHYS(j)] = v;
        }
    }
    __syncthreads();

    // ---------------- phase E (conjugate mirror, chained base) ------------
    {
        float bs, bc; fsincos(-(TWO_PI / 4096.0f) * (float)t, &bs, &bc);
        const float SC =  0.923879532511287f;   // cos(pi/8)
        const float SS = -0.382683432365090f;   // sin(-pi/8)
        #pragma unroll 4
        for (int ii = 0; ii < 8; ii++) {
            const int f = t + 256 * ii;                // 0..2047
            const float wc = bc, ws = bs;              // e^{-2pi i f/4096}
            { const float nr = bc * SC - bs * SS;      // advance base
              const float ni = bc * SS + bs * SC;
              bc = nr; bs = ni; }
            float cr = 1.0f, ci = 0.0f, Cr = 0.0f, Ci = 0.0f;
            #pragma unroll
            for (int k = 0; k < NCOEF; k++) {
                const float cc = csh[k];
                Cr += cc * cr; Ci += cc * ci;
                const float nr = cr * wc - ci * ws;
                const float ni = cr * ws + ci * wc;
                cr = nr; ci = ni;
            }
            const float m = __expf(Cr);
            float si, co; fsincos(Ci, &si, &co);
            const float er = m * co, ei = m * si;
            EHr[f] = er; EHi[f] = ei;
            if (f > 0) { EHr[4096 - f] = er; EHi[4096 - f] = -ei; }
        }
        if (t == 0) {                                  // f = 2048
            float Cr = 0.0f, Ci = 0.0f;
            float cr = 1.0f, ci = 0.0f;
            #pragma unroll
            for (int k = 0; k < NCOEF; k++) {
                Cr += csh[k] * cr; Ci += csh[k] * ci;
                cr = -cr; ci = -ci;                    // e^{-i pi k} = (-1)^k
            }
            const float m = __expf(Cr);
            float si, co; fsincos(Ci, &si, &co);
            EHr[2048] = m * co; EHi[2048] = m * si;
        }
    }
    __syncthreads();

    // ---------------- stage 1 (R12 shape, Hermitian mask b<=32) ------------
    {
        const bool act = (t & 15) < 9;         // b-groups 0..8 (b0 = 0..32)
        const int b0 = (t & 15) * 4;
        const int d0 = (t >> 4) * 2;           // 0,2,...,30
        float Ter[2][4], Tei[2][4], Tor[2][4], Toi[2][4];
        #pragma unroll
        for (int j = 0; j < 2; j++)
            #pragma unroll
            for (int i = 0; i < 4; i++) {
                Ter[j][i] = 0.0f; Tei[j][i] = 0.0f;
                Tor[j][i] = 0.0f; Toi[j][i] = 0.0f;
            }
        float rr[2], ri[2], wr[2], wi[2];
        #pragma unroll
        for (int j = 0; j < 2; j++) {
            float s, c; fsincos((TWO_PI / 32.0f) * (float)(d0 + j), &s, &c);
            wr[j] = c; wi[j] = s; rr[j] = 1.0f; ri[j] = 0.0f;
        }
        if (act) {
            // explicit prefetch double-buffer over a2 (R12 verbatim)
            float4 vre = *(const float4*)&EHr[b0];
            float4 vie = *(const float4*)&EHi[b0];
            float4 vro = *(const float4*)&EHr[64 + b0];
            float4 vio = *(const float4*)&EHi[64 + b0];
            #pragma unroll 4
            for (int a2 = 0; a2 < 32; a2++) {
                const float4 cre = vre, cie = vie, cro = vro, cio = vio;
                if (a2 < 31) {
                    const int nb = 128 * (a2 + 1) + b0;
                    vre = *(const float4*)&EHr[nb];
                    vie = *(const float4*)&EHi[nb];
                    vro = *(const float4*)&EHr[nb + 64];
                    vio = *(const float4*)&EHi[nb + 64];
                }
                const float ere[4] = {cre.x, cre.y, cre.z, cre.w};
                const float eie[4] = {cie.x, cie.y, cie.z, cie.w};
                const float ero[4] = {cro.x, cro.y, cro.z, cro.w};
                const float eio[4] = {cio.x, cio.y, cio.z, cio.w};
                #pragma unroll
                for (int j = 0; j < 2; j++) {
                    #pragma unroll
                    for (int i = 0; i < 4; i++) {
                        Ter[j][i] += ere[i] * rr[j] - eie[i] * ri[j];
                        Tei[j][i] += ere[i] * ri[j] + eie[i] * rr[j];
                        Tor[j][i] += ero[i] * rr[j] - eio[i] * ri[j];
                        Toi[j][i] += ero[i] * ri[j] + eio[i] * rr[j];
                    }
                    const float nr = rr[j] * wr[j] - ri[j] * wi[j];
                    const float ni = rr[j] * wi[j] + ri[j] * wr[j];
                    rr[j] = nr; ri[j] = ni;
                }
            }
        }
        __syncthreads();   // uniform barrier: ALL E reads done before G' store

        if (act) {
            // radix-2 butterfly + bd/4096 twiddle + store (b <= 32 only)
            float os[2], oc[2];
            #pragma unroll
            for (int j = 0; j < 2; j++)
                fsincos((TWO_PI / 64.0f) * (float)(d0 + j), &os[j], &oc[j]);
            #pragma unroll
            for (int i = 0; i < 4; i++) {
                const int b = b0 + i;
                if (b > 32) continue;
                float gpr[2], gpi[2], gmr[2], gmi[2];
                #pragma unroll
                for (int j = 0; j < 2; j++) {
                    const int d = d0 + j;
                    const float ur = oc[j] * Tor[j][i] - os[j] * Toi[j][i];
                    const float ui = oc[j] * Toi[j][i] + os[j] * Tor[j][i];
                    const float pr = Ter[j][i] + ur, pi = Tei[j][i] + ui;
                    const float mr = Ter[j][i] - ur, mi = Tei[j][i] - ui;
                    float s, c;
                    fsincos((TWO_PI / 4096.0f) * (float)(b * d), &s, &c);
                    gpr[j] = pr * c - pi * s; gpi[j] = pr * s + pi * c;
                    fsincos((TWO_PI / 4096.0f) * (float)(b * (d + 32)), &s, &c);
                    gmr[j] = mr * c - mi * s; gmi[j] = mr * s + mi * c;
                }
                *(float2*)&Gr[b * GS + d0]      = make_float2(gpr[0], gpr[1]);
                *(float2*)&Gi[b * GS + d0]      = make_float2(gpi[0], gpi[1]);
                *(float2*)&Gr[b * GS + d0 + 32] = make_float2(gmr[0], gmr[1]);
                *(float2*)&Gi[b * GS + d0 + 32] = make_float2(gmi[0], gmi[1]);
            }
        }
    }
    __syncthreads();

    // ---------------- stage 2 (Hermitian 31 STEP2s + boundary, R13 math) --
    float hv[4][2];
    int   dl_, cg_;
    {
        const int dl = (t & 31) * 2;
        const int cg = t >> 5;                     // 0..7
        dl_ = dl; cg_ = cg;
        float swi_, swr_; fsincos((TWO_PI / 64.0f) * (float)cg, &swi_, &swr_);
        const float swr = swr_, swi = swi_;        // step e^{2pi i cg/64}
        float rr = swr, ri = swi;                  // chain at b = 1
        float acc00 = 0, acc01 = 0, acc10 = 0, acc11 = 0;
        float acc20 = 0, acc21 = 0, acc30 = 0, acc31 = 0;
        int bb = 1;

#define S2C 0.70710678118654752f
#define STEP2(f8r, f8i, f16r, f16i, f24r, f24i)                                \
        {                                                                      \
            const float2 g_r = *(const float2*)&Gr[bb * GS + dl];              \
            const float2 g_i = *(const float2*)&Gi[bb * GS + dl];              \
            acc00 += g_r.x * rr - g_i.x * ri;                                  \
            acc01 += g_r.y * rr - g_i.y * ri;                                  \
            { const float tr = rr*(f8r) - ri*(f8i), ti = rr*(f8i) + ri*(f8r);  \
              acc10 += g_r.x * tr - g_i.x * ti;                                \
              acc11 += g_r.y * tr - g_i.y * ti; }                              \
            { const float tr = rr*(f16r) - ri*(f16i), ti = rr*(f16i) + ri*(f16r); \
              acc20 += g_r.x * tr - g_i.x * ti;                                \
              acc21 += g_r.y * tr - g_i.y * ti; }                              \
            { const float tr = rr*(f24r) - ri*(f24i), ti = rr*(f24i) + ri*(f24r); \
              acc30 += g_r.x * tr - g_i.x * ti;                                \
              acc31 += g_r.y * tr - g_i.y * ti; }                              \
            { const float nr = rr * swr - ri * swi;                            \
              const float ni = rr * swi + ri * swr;                            \
              rr = nr; ri = ni; }                                              \
            bb++;                                                              \
        }

        // b = 1..7 (patterns u = 1..7)
        STEP2( S2C,  S2C,    0.0f, 1.0f,  -S2C,  S2C)
        STEP2( 0.0f, 1.0f,  -1.0f, 0.0f,   0.0f,-1.0f)
        STEP2(-S2C,  S2C,    0.0f,-1.0f,   S2C,  S2C)
        STEP2(-1.0f, 0.0f,   1.0f, 0.0f,  -1.0f, 0.0f)
        STEP2(-S2C, -S2C,    0.0f, 1.0f,   S2C, -S2C)
        STEP2( 0.0f,-1.0f,  -1.0f, 0.0f,   0.0f, 1.0f)
        STEP2( S2C, -S2C,    0.0f,-1.0f,  -S2C, -S2C)
        // b = 8..31 (3 full groups of 8)
        for (int grp = 0; grp < 3; grp++) {
            STEP2( 1.0f, 0.0f,   1.0f, 0.0f,   1.0f, 0.0f)
            STEP2( S2C,  S2C,    0.0f, 1.0f,  -S2C,  S2C)
            STEP2( 0.0f, 1.0f,  -1.0f, 0.0f,   0.0f,-1.0f)
            STEP2(-S2C,  S2C,    0.0f,-1.0f,   S2C,  S2C)
            STEP2(-1.0f, 0.0f,   1.0f, 0.0f,  -1.0f, 0.0f)
            STEP2(-S2C, -S2C,    0.0f, 1.0f,   S2C, -S2C)
            STEP2( 0.0f,-1.0f,  -1.0f, 0.0f,   0.0f, 1.0f)
            STEP2( S2C, -S2C,    0.0f,-1.0f,  -S2C, -S2C)
        }
#undef STEP2

        // boundary terms b=0 and b=32 (rows real by symmetry; use Re only)
        const float g0a  = Gr[dl],           g0b  = Gr[dl + 1];
        const float g32a = Gr[32 * GS + dl], g32b = Gr[32 * GS + dl + 1];
        const float sgn  = (cg & 1) ? -1.0f : 1.0f;   // (-1)^{cg+8v} = (-1)^cg
        const float sc = 1.0f / 4096.0f;
        hv[0][0] = (g0a + sgn * g32a + 2.0f * acc00) * sc;
        hv[0][1] = (g0b + sgn * g32b + 2.0f * acc01) * sc;
        hv[1][0] = (g0a + sgn * g32a + 2.0f * acc10) * sc;
        hv[1][1] = (g0b + sgn * g32b + 2.0f * acc11) * sc;
        hv[2][0] = (g0a + sgn * g32a + 2.0f * acc20) * sc;
        hv[2][1] = (g0b + sgn * g32b + 2.0f * acc21) * sc;
        hv[3][0] = (g0a + sgn * g32a + 2.0f * acc30) * sc;
        hv[3][1] = (g0b + sgn * g32b + 2.0f * acc31) * sc;
    }
    __syncthreads();   // all G reads done; U is free

    // ---------------- h -> LDS ----------------
    #pragma unroll
    for (int v = 0; v < 4; v++) {
        const int c = cg_ + 8 * v;
        const int n = 64 * c + dl_;
        if (n < IR_LEN)     hU[n]     = hv[v][0];
        if (n + 1 < IR_LEN) hU[n + 1] = hv[v][1];
    }
    __syncthreads();

    // ---------------- FIR: z[o], o in [0,160) ----------------
    if (t < 240) {
        const int o0 = (t % 20) * 8;
        const int kc = t / 20;                 // 0..11
        const int kb = kc * 168;
        const int ns = (kc == 11) ? 38 : 42;   // 11*168=1848, +152 = 2000
        float s0[8] = {0,0,0,0,0,0,0,0};
        int Bo = o0 + 1996 - kb;               // mult of 4, >= 0
        float4 w1 = *(const float4*)&xws[XPHYS(Bo + 4)];
        float4 w2 = *(const float4*)&xws[XPHYS(Bo + 8)];
        for (int s = 0; s < ns; s++) {
            const float4 w0 = *(const float4*)&xws[XPHYS(Bo)];
            const float4 ha = *(const float4*)&hU[kb + 4 * s];
            const float wv[12] = {w0.x, w0.y, w0.z, w0.w,
                                  w1.x, w1.y, w1.z, w1.w,
                                  w2.x, w2.y, w2.z, w2.w};
            const float hav[4] = {ha.x, ha.y, ha.z, ha.w};
            #pragma unroll
            for (int jo = 0; jo < 8; jo++) {
                #pragma unroll
                for (int jk = 0; jk < 4; jk++) {
                    s0[jo] += hav[jk] * wv[3 + jo - jk];
                }
            }
            w2 = w1; w1 = w0; Bo -= 4;
        }
        const int rb = kc * 168 + o0;
        *(float4*)&red[rb]     = make_float4(s0[0], s0[1], s0[2], s0[3]);
        *(float4*)&red[rb + 4] = make_float4(s0[4], s0[5], s0[6], s0[7]);
    }
    __syncthreads();

    // ---------------- epilogue: tent-weighted atomic scatter ----------------
    if (t < 160) {
        float z = 0.0f;
        #pragma unroll
        for (int kc = 0; kc < 12; kc++) z += red[kc * 168 + t];
        const int o = t;
        const int tout = t0 - PFRAME + o;
        float wgt = (o < PFRAME) ? (float)o * (1.0f / PFRAME)
                                 : (float)(160 - o) * (1.0f / PFRAME);
        if (frame == NFRAMES - 1 && o >= PFRAME) wgt = 1.0f;  // clamped h_next
        if (tout >= 0) {                       // frame 0 has no previous frame
            atomicAdd(&y[batch * T_TOTAL + tout], wgt * z);
        }
    }
}

extern "C" void kernel_launch(void* const* d_in, const int* in_sizes, int n_in,
                              void* d_out, int out_size, void* d_ws, size_t ws_size,
                              hipStream_t stream) {
    const float* x  = (const float*)d_in[0];   // (2, 24000)
    const float* mc = (const float*)d_in[1];   // (2, 300, 25)
    float* y = (float*)d_out;                  // (2, 24000)

    hipMemsetAsync(y, 0, (size_t)out_size * sizeof(float), stream);
    minphase_fir_fused<<<NROWS, 256, 0, stream>>>(mc, x, y);
}

// Round 16
// 91.114 us; speedup vs baseline: 1.2044x; 1.2044x over previous
//
#include <hip/hip_runtime.h>
#include <math.h>

#define IR_LEN  2000
#define PFRAME  80
#define NFRAMES 300
#define NBATCH  2
#define NROWS   (NBATCH*NFRAMES)     // 600
#define T_TOTAL (NFRAMES*PFRAME)     // 24000
#define NCOEF   25
#define TWO_PI  6.283185307179586f
#define GS      68                   // G row stride in floats
#define XWN     2160                 // logical x-window floats per block
#define XWPAD   2432                 // physical (4-float pad per 32)

#define XPHYS(B) ((B) + (((B) >> 5) << 2))

__device__ __forceinline__ void fsincos(float a, float* s, float* c) {
    *s = __sinf(a); *c = __cosf(a);
}

// ---------------------------------------------------------------------------
// Fully fused kernel: one block per (batch,frame) row. 600 blocks, 256 thr.
// R12 code shape (proven VGPR 72 / 46 us) + Hermitian fold with stage 2 kept
// BYTE-IDENTICAL in shape to R12's rolled loop (R13/14/15 post-mortem: the
// straight-line 31-STEP2 variant is what blew VGPR to ~172):
//   - stage 1: R12 shape; threads with (t&15) > 8 masked (redundant b-cols,
//     G'[d][64-b] = conj G'[d][b]); store guarded to b <= 32.
//   - stage 2: R12's 8-STEP2 group loop, 4 groups (b = 0..31), forced rolled
//     (#pragma unroll 1). b=0 lands in acc with weight 1; Hermitian fixup:
//     h = (2*acc - g0 + (-1)^cg * g32) / 4096.
// Everything else (x-stage, E phase, FIR, epilogue) is R12 verbatim.
// ---------------------------------------------------------------------------
__global__ __launch_bounds__(256) void minphase_fir_fused(
        const float* __restrict__ mc, const float* __restrict__ x,
        float* __restrict__ y) {
    __shared__ __align__(16) float U[8704];    // 34.8 KB union
    __shared__ __align__(16) float xws[XWPAD]; // 9.7 KB padded x window
    __shared__ float csh[NCOEF];
    float* const EHr = U;                      // [4096]      (phase E)
    float* const EHi = U + 4096;               // [4096]
    float* const Gr  = U;                      // [rows b<=32] (stages 1/2)
    float* const Gi  = U + 4352;               // [rows b<=32]
    float* const hU  = U;                      // [2000]      (FIR phase)
    float* const red = U + 4224;               // [12 rows, stride 168]

    const int row   = blockIdx.x;
    const int batch = row / NFRAMES;
    const int frame = row - batch * NFRAMES;
    const int t0    = frame * PFRAME;
    const int t     = threadIdx.x;

    if (t < NCOEF) csh[t] = mc[row * NCOEF + t];

    // ---------------- stage x: pre-stage x window (padded) ----------------
    {
        const float* xb = x + batch * T_TOTAL;
        for (int j = t; j < XWN; j += 256) {
            const int xi = t0 - 2079 + j;
            const float v = (xi >= 0 && xi < T_TOTAL) ? xb[xi] : 0.0f;
            xws[XPHYS(j)] = v;
        }
    }
    __syncthreads();

    // ---------------- phase E (conjugate mirror, chained base) ------------
    {
        float bs, bc; fsincos(-(TWO_PI / 4096.0f) * (float)t, &bs, &bc);
        const float SC =  0.923879532511287f;   // cos(pi/8)
        const float SS = -0.382683432365090f;   // sin(-pi/8)
        #pragma unroll 4
        for (int ii = 0; ii < 8; ii++) {
            const int f = t + 256 * ii;                // 0..2047
            const float wc = bc, ws = bs;              // e^{-2pi i f/4096}
            { const float nr = bc * SC - bs * SS;      // advance base
              const float ni = bc * SS + bs * SC;
              bc = nr; bs = ni; }
            float cr = 1.0f, ci = 0.0f, Cr = 0.0f, Ci = 0.0f;
            #pragma unroll
            for (int k = 0; k < NCOEF; k++) {
                const float cc = csh[k];
                Cr += cc * cr; Ci += cc * ci;
                const float nr = cr * wc - ci * ws;
                const float ni = cr * ws + ci * wc;
                cr = nr; ci = ni;
            }
            const float m = __expf(Cr);
            float si, co; fsincos(Ci, &si, &co);
            const float er = m * co, ei = m * si;
            EHr[f] = er; EHi[f] = ei;
            if (f > 0) { EHr[4096 - f] = er; EHi[4096 - f] = -ei; }
        }
        if (t == 0) {                                  // f = 2048
            float Cr = 0.0f, Ci = 0.0f;
            float cr = 1.0f, ci = 0.0f;
            #pragma unroll
            for (int k = 0; k < NCOEF; k++) {
                Cr += csh[k] * cr; Ci += csh[k] * ci;
                cr = -cr; ci = -ci;                    // e^{-i pi k} = (-1)^k
            }
            const float m = __expf(Cr);
            float si, co; fsincos(Ci, &si, &co);
            EHr[2048] = m * co; EHi[2048] = m * si;
        }
    }
    __syncthreads();

    // ---------------- stage 1 (R12 shape, Hermitian mask b<=32) ------------
    {
        const bool act = (t & 15) < 9;         // b-groups 0..8 (b0 = 0..32)
        const int b0 = (t & 15) * 4;
        const int d0 = (t >> 4) * 2;           // 0,2,...,30
        float Ter[2][4], Tei[2][4], Tor[2][4], Toi[2][4];
        #pragma unroll
        for (int j = 0; j < 2; j++)
            #pragma unroll
            for (int i = 0; i < 4; i++) {
                Ter[j][i] = 0.0f; Tei[j][i] = 0.0f;
                Tor[j][i] = 0.0f; Toi[j][i] = 0.0f;
            }
        float rr[2], ri[2], wr[2], wi[2];
        #pragma unroll
        for (int j = 0; j < 2; j++) {
            float s, c; fsincos((TWO_PI / 32.0f) * (float)(d0 + j), &s, &c);
            wr[j] = c; wi[j] = s; rr[j] = 1.0f; ri[j] = 0.0f;
        }
        if (act) {
            // explicit prefetch double-buffer over a2 (R12 verbatim)
            float4 vre = *(const float4*)&EHr[b0];
            float4 vie = *(const float4*)&EHi[b0];
            float4 vro = *(const float4*)&EHr[64 + b0];
            float4 vio = *(const float4*)&EHi[64 + b0];
            #pragma unroll 4
            for (int a2 = 0; a2 < 32; a2++) {
                const float4 cre = vre, cie = vie, cro = vro, cio = vio;
                if (a2 < 31) {
                    const int nb = 128 * (a2 + 1) + b0;
                    vre = *(const float4*)&EHr[nb];
                    vie = *(const float4*)&EHi[nb];
                    vro = *(const float4*)&EHr[nb + 64];
                    vio = *(const float4*)&EHi[nb + 64];
                }
                const float ere[4] = {cre.x, cre.y, cre.z, cre.w};
                const float eie[4] = {cie.x, cie.y, cie.z, cie.w};
                const float ero[4] = {cro.x, cro.y, cro.z, cro.w};
                const float eio[4] = {cio.x, cio.y, cio.z, cio.w};
                #pragma unroll
                for (int j = 0; j < 2; j++) {
                    #pragma unroll
                    for (int i = 0; i < 4; i++) {
                        Ter[j][i] += ere[i] * rr[j] - eie[i] * ri[j];
                        Tei[j][i] += ere[i] * ri[j] + eie[i] * rr[j];
                        Tor[j][i] += ero[i] * rr[j] - eio[i] * ri[j];
                        Toi[j][i] += ero[i] * ri[j] + eio[i] * rr[j];
                    }
                    const float nr = rr[j] * wr[j] - ri[j] * wi[j];
                    const float ni = rr[j] * wi[j] + ri[j] * wr[j];
                    rr[j] = nr; ri[j] = ni;
                }
            }
        }
        __syncthreads();   // uniform barrier: ALL E reads done before G' store

        if (act) {
            // radix-2 butterfly + bd/4096 twiddle + store (b <= 32 only)
            float os[2], oc[2];
            #pragma unroll
            for (int j = 0; j < 2; j++)
                fsincos((TWO_PI / 64.0f) * (float)(d0 + j), &os[j], &oc[j]);
            #pragma unroll
            for (int i = 0; i < 4; i++) {
                const int b = b0 + i;
                if (b > 32) continue;
                float gpr[2], gpi[2], gmr[2], gmi[2];
                #pragma unroll
                for (int j = 0; j < 2; j++) {
                    const int d = d0 + j;
                    const float ur = oc[j] * Tor[j][i] - os[j] * Toi[j][i];
                    const float ui = oc[j] * Toi[j][i] + os[j] * Tor[j][i];
                    const float pr = Ter[j][i] + ur, pi = Tei[j][i] + ui;
                    const float mr = Ter[j][i] - ur, mi = Tei[j][i] - ui;
                    float s, c;
                    fsincos((TWO_PI / 4096.0f) * (float)(b * d), &s, &c);
                    gpr[j] = pr * c - pi * s; gpi[j] = pr * s + pi * c;
                    fsincos((TWO_PI / 4096.0f) * (float)(b * (d + 32)), &s, &c);
                    gmr[j] = mr * c - mi * s; gmi[j] = mr * s + mi * c;
                }
                *(float2*)&Gr[b * GS + d0]      = make_float2(gpr[0], gpr[1]);
                *(float2*)&Gi[b * GS + d0]      = make_float2(gpi[0], gpi[1]);
                *(float2*)&Gr[b * GS + d0 + 32] = make_float2(gmr[0], gmr[1]);
                *(float2*)&Gi[b * GS + d0 + 32] = make_float2(gmi[0], gmi[1]);
            }
        }
    }
    __syncthreads();

    // ---------------- stage 2 (R12 rolled loop, 4 groups = b 0..31) -------
    float hv[4][2];
    int   dl_, cg_;
    {
        const int dl = (t & 31) * 2;
        const int cg = t >> 5;                     // 0..7
        dl_ = dl; cg_ = cg;
        float swi_, swr_; fsincos((TWO_PI / 64.0f) * (float)cg, &swi_, &swr_);
        const float swr = swr_, swi = swi_;        // step e^{2pi i cg/64}
        float rr = 1.0f, ri = 0.0f;
        float acc00 = 0, acc01 = 0, acc10 = 0, acc11 = 0;
        float acc20 = 0, acc21 = 0, acc30 = 0, acc31 = 0;
        int bb = 0;

#define S2C 0.70710678118654752f
#define STEP2(f8r, f8i, f16r, f16i, f24r, f24i)                                \
        {                                                                      \
            const float2 g_r = *(const float2*)&Gr[bb * GS + dl];              \
            const float2 g_i = *(const float2*)&Gi[bb * GS + dl];              \
            acc00 += g_r.x * rr - g_i.x * ri;                                  \
            acc01 += g_r.y * rr - g_i.y * ri;                                  \
            { const float tr = rr*(f8r) - ri*(f8i), ti = rr*(f8i) + ri*(f8r);  \
              acc10 += g_r.x * tr - g_i.x * ti;                                \
              acc11 += g_r.y * tr - g_i.y * ti; }                              \
            { const float tr = rr*(f16r) - ri*(f16i), ti = rr*(f16i) + ri*(f16r); \
              acc20 += g_r.x * tr - g_i.x * ti;                                \
              acc21 += g_r.y * tr - g_i.y * ti; }                              \
            { const float tr = rr*(f24r) - ri*(f24i), ti = rr*(f24i) + ri*(f24r); \
              acc30 += g_r.x * tr - g_i.x * ti;                                \
              acc31 += g_r.y * tr - g_i.y * ti; }                              \
            { const float nr = rr * swr - ri * swi;                            \
              const float ni = rr * swi + ri * swr;                            \
              rr = nr; ri = ni; }                                              \
            bb++;                                                              \
        }

        #pragma unroll 1
        for (int grp = 0; grp < 4; grp++) {        // b = 0..31 (rolled!)
            STEP2( 1.0f, 0.0f,   1.0f, 0.0f,   1.0f, 0.0f)
            STEP2( S2C,  S2C,    0.0f, 1.0f,  -S2C,  S2C)
            STEP2( 0.0f, 1.0f,  -1.0f, 0.0f,   0.0f,-1.0f)
            STEP2(-S2C,  S2C,    0.0f,-1.0f,   S2C,  S2C)
            STEP2(-1.0f, 0.0f,   1.0f, 0.0f,  -1.0f, 0.0f)
            STEP2(-S2C, -S2C,    0.0f, 1.0f,   S2C, -S2C)
            STEP2( 0.0f,-1.0f,  -1.0f, 0.0f,   0.0f, 1.0f)
            STEP2( S2C, -S2C,    0.0f,-1.0f,  -S2C, -S2C)
        }
#undef STEP2

        // Hermitian fixup: loop counted b=0 once in every acc; true sum is
        //   g0 + (-1)^cg * g32 + 2 * sum_{b=1..31} = 2*acc - g0 + sgn*g32
        const float g0a  = Gr[dl],           g0b  = Gr[dl + 1];
        const float g32a = Gr[32 * GS + dl], g32b = Gr[32 * GS + dl + 1];
        const float sgn  = (cg & 1) ? -1.0f : 1.0f;   // (-1)^{cg+8v} = (-1)^cg
        const float sc = 1.0f / 4096.0f;
        hv[0][0] = (2.0f * acc00 - g0a + sgn * g32a) * sc;
        hv[0][1] = (2.0f * acc01 - g0b + sgn * g32b) * sc;
        hv[1][0] = (2.0f * acc10 - g0a + sgn * g32a) * sc;
        hv[1][1] = (2.0f * acc11 - g0b + sgn * g32b) * sc;
        hv[2][0] = (2.0f * acc20 - g0a + sgn * g32a) * sc;
        hv[2][1] = (2.0f * acc21 - g0b + sgn * g32b) * sc;
        hv[3][0] = (2.0f * acc30 - g0a + sgn * g32a) * sc;
        hv[3][1] = (2.0f * acc31 - g0b + sgn * g32b) * sc;
    }
    __syncthreads();   // all G reads done; U is free

    // ---------------- h -> LDS ----------------
    #pragma unroll
    for (int v = 0; v < 4; v++) {
        const int c = cg_ + 8 * v;
        const int n = 64 * c + dl_;
        if (n < IR_LEN)     hU[n]     = hv[v][0];
        if (n + 1 < IR_LEN) hU[n + 1] = hv[v][1];
    }
    __syncthreads();

    // ---------------- FIR: z[o], o in [0,160) ----------------
    if (t < 240) {
        const int o0 = (t % 20) * 8;
        const int kc = t / 20;                 // 0..11
        const int kb = kc * 168;
        const int ns = (kc == 11) ? 38 : 42;   // 11*168=1848, +152 = 2000
        float s0[8] = {0,0,0,0,0,0,0,0};
        int Bo = o0 + 1996 - kb;               // mult of 4, >= 0
        float4 w1 = *(const float4*)&xws[XPHYS(Bo + 4)];
        float4 w2 = *(const float4*)&xws[XPHYS(Bo + 8)];
        for (int s = 0; s < ns; s++) {
            const float4 w0 = *(const float4*)&xws[XPHYS(Bo)];
            const float4 ha = *(const float4*)&hU[kb + 4 * s];
            const float wv[12] = {w0.x, w0.y, w0.z, w0.w,
                                  w1.x, w1.y, w1.z, w1.w,
                                  w2.x, w2.y, w2.z, w2.w};
            const float hav[4] = {ha.x, ha.y, ha.z, ha.w};
            #pragma unroll
            for (int jo = 0; jo < 8; jo++) {
                #pragma unroll
                for (int jk = 0; jk < 4; jk++) {
                    s0[jo] += hav[jk] * wv[3 + jo - jk];
                }
            }
            w2 = w1; w1 = w0; Bo -= 4;
        }
        const int rb = kc * 168 + o0;
        *(float4*)&red[rb]     = make_float4(s0[0], s0[1], s0[2], s0[3]);
        *(float4*)&red[rb + 4] = make_float4(s0[4], s0[5], s0[6], s0[7]);
    }
    __syncthreads();

    // ---------------- epilogue: tent-weighted atomic scatter ----------------
    if (t < 160) {
        float z = 0.0f;
        #pragma unroll
        for (int kc = 0; kc < 12; kc++) z += red[kc * 168 + t];
        const int o = t;
        const int tout = t0 - PFRAME + o;
        float wgt = (o < PFRAME) ? (float)o * (1.0f / PFRAME)
                                 : (float)(160 - o) * (1.0f / PFRAME);
        if (frame == NFRAMES - 1 && o >= PFRAME) wgt = 1.0f;  // clamped h_next
        if (tout >= 0) {                       // frame 0 has no previous frame
            atomicAdd(&y[batch * T_TOTAL + tout], wgt * z);
        }
    }
}

extern "C" void kernel_launch(void* const* d_in, const int* in_sizes, int n_in,
                              void* d_out, int out_size, void* d_ws, size_t ws_size,
                              hipStream_t stream) {
    const float* x  = (const float*)d_in[0];   // (2, 24000)
    const float* mc = (const float*)d_in[1];   // (2, 300, 25)
    float* y = (float*)d_out;                  // (2, 24000)

    hipMemsetAsync(y, 0, (size_t)out_size * sizeof(float), stream);
    minphase_fir_fused<<<NROWS, 256, 0, stream>>>(mc, x, y);
}

// Round 17
// 90.218 us; speedup vs baseline: 1.2164x; 1.0099x over previous
//
#include <hip/hip_runtime.h>
#include <math.h>

#define IR_LEN  2000
#define PFRAME  80
#define NFRAMES 300
#define NBATCH  2
#define NROWS   (NBATCH*NFRAMES)     // 600
#define T_TOTAL (NFRAMES*PFRAME)     // 24000
#define NCOEF   25
#define TWO_PI  6.283185307179586f
#define GS      68                   // G row stride in floats
#define XWN     2160                 // logical x-window floats per block
#define XWPAD   2432                 // physical (4-float pad per 32)

#define XPHYS(B) ((B) + (((B) >> 5) << 2))

__device__ __forceinline__ void fsincos(float a, float* s, float* c) {
    *s = __sinf(a); *c = __cosf(a);
}

// ---------------------------------------------------------------------------
// Fully fused kernel: one block per (batch,frame) row. 600 blocks, 256 thr.
// R16 (proven VGPR 72 / 42 us / total 91 us) + ONE change: stage-1 Hermitian
// mask moved from lane-interleaved ((t&15)<9: 9/16 lanes of EVERY wave) to
// WAVE-CONTIGUOUS (t<144: waves 0-1 dense, wave 2 quarter, wave 3 skips via
// execz) -> stage-1 VALU issue slots drop ~40%, freeing the shared SIMDs for
// co-resident blocks. Tile shape / loops / layout byte-identical to R16.
//   - stage 1: radix-2 over a, 4b x 2d tile, b-group = t%9 (b0 = 0..32),
//     d-pair = t/9; store guarded to b <= 32 (G'[d][64-b] = conj G'[d][b]).
//   - stage 2: R16's rolled 8-STEP2 loop, 4 groups (b = 0..31), Hermitian
//     fixup h = (2*acc - g0 + (-1)^cg * g32) / 4096.
// Everything else (x-stage, E phase, FIR, epilogue) is R16 verbatim.
// ---------------------------------------------------------------------------
__global__ __launch_bounds__(256) void minphase_fir_fused(
        const float* __restrict__ mc, const float* __restrict__ x,
        float* __restrict__ y) {
    __shared__ __align__(16) float U[8704];    // 34.8 KB union
    __shared__ __align__(16) float xws[XWPAD]; // 9.7 KB padded x window
    __shared__ float csh[NCOEF];
    float* const EHr = U;                      // [4096]      (phase E)
    float* const EHi = U + 4096;               // [4096]
    float* const Gr  = U;                      // [rows b<=32] (stages 1/2)
    float* const Gi  = U + 4352;               // [rows b<=32]
    float* const hU  = U;                      // [2000]      (FIR phase)
    float* const red = U + 4224;               // [12 rows, stride 168]

    const int row   = blockIdx.x;
    const int batch = row / NFRAMES;
    const int frame = row - batch * NFRAMES;
    const int t0    = frame * PFRAME;
    const int t     = threadIdx.x;

    if (t < NCOEF) csh[t] = mc[row * NCOEF + t];

    // ---------------- stage x: pre-stage x window (padded) ----------------
    {
        const float* xb = x + batch * T_TOTAL;
        for (int j = t; j < XWN; j += 256) {
            const int xi = t0 - 2079 + j;
            const float v = (xi >= 0 && xi < T_TOTAL) ? xb[xi] : 0.0f;
            xws[XPHYS(j)] = v;
        }
    }
    __syncthreads();

    // ---------------- phase E (conjugate mirror, chained base) ------------
    {
        float bs, bc; fsincos(-(TWO_PI / 4096.0f) * (float)t, &bs, &bc);
        const float SC =  0.923879532511287f;   // cos(pi/8)
        const float SS = -0.382683432365090f;   // sin(-pi/8)
        #pragma unroll 4
        for (int ii = 0; ii < 8; ii++) {
            const int f = t + 256 * ii;                // 0..2047
            const float wc = bc, ws = bs;              // e^{-2pi i f/4096}
            { const float nr = bc * SC - bs * SS;      // advance base
              const float ni = bc * SS + bs * SC;
              bc = nr; bs = ni; }
            float cr = 1.0f, ci = 0.0f, Cr = 0.0f, Ci = 0.0f;
            #pragma unroll
            for (int k = 0; k < NCOEF; k++) {
                const float cc = csh[k];
                Cr += cc * cr; Ci += cc * ci;
                const float nr = cr * wc - ci * ws;
                const float ni = cr * ws + ci * wc;
                cr = nr; ci = ni;
            }
            const float m = __expf(Cr);
            float si, co; fsincos(Ci, &si, &co);
            const float er = m * co, ei = m * si;
            EHr[f] = er; EHi[f] = ei;
            if (f > 0) { EHr[4096 - f] = er; EHi[4096 - f] = -ei; }
        }
        if (t == 0) {                                  // f = 2048
            float Cr = 0.0f, Ci = 0.0f;
            float cr = 1.0f, ci = 0.0f;
            #pragma unroll
            for (int k = 0; k < NCOEF; k++) {
                Cr += csh[k] * cr; Ci += csh[k] * ci;
                cr = -cr; ci = -ci;                    // e^{-i pi k} = (-1)^k
            }
            const float m = __expf(Cr);
            float si, co; fsincos(Ci, &si, &co);
            EHr[2048] = m * co; EHi[2048] = m * si;
        }
    }
    __syncthreads();

    // ------- stage 1 (R16 shape, wave-contiguous Hermitian tiles) ---------
    {
        const bool act = t < 144;              // waves 0-1 dense, w2 1/4, w3 off
        const int bg = t % 9;                  // b-group 0..8  (b0 = 0..32)
        const int dp = t / 9;                  // d-pair 0..15  (for t < 144)
        const int b0 = bg * 4;
        const int d0 = dp * 2;
        float Ter[2][4], Tei[2][4], Tor[2][4], Toi[2][4];
        #pragma unroll
        for (int j = 0; j < 2; j++)
            #pragma unroll
            for (int i = 0; i < 4; i++) {
                Ter[j][i] = 0.0f; Tei[j][i] = 0.0f;
                Tor[j][i] = 0.0f; Toi[j][i] = 0.0f;
            }
        float rr[2], ri[2], wr[2], wi[2];
        if (act) {
            #pragma unroll
            for (int j = 0; j < 2; j++) {
                float s, c; fsincos((TWO_PI / 32.0f) * (float)(d0 + j), &s, &c);
                wr[j] = c; wi[j] = s; rr[j] = 1.0f; ri[j] = 0.0f;
            }
            // explicit prefetch double-buffer over a2 (R16 verbatim)
            float4 vre = *(const float4*)&EHr[b0];
            float4 vie = *(const float4*)&EHi[b0];
            float4 vro = *(const float4*)&EHr[64 + b0];
            float4 vio = *(const float4*)&EHi[64 + b0];
            #pragma unroll 4
            for (int a2 = 0; a2 < 32; a2++) {
                const float4 cre = vre, cie = vie, cro = vro, cio = vio;
                if (a2 < 31) {
                    const int nb = 128 * (a2 + 1) + b0;
                    vre = *(const float4*)&EHr[nb];
                    vie = *(const float4*)&EHi[nb];
                    vro = *(const float4*)&EHr[nb + 64];
                    vio = *(const float4*)&EHi[nb + 64];
                }
                const float ere[4] = {cre.x, cre.y, cre.z, cre.w};
                const float eie[4] = {cie.x, cie.y, cie.z, cie.w};
                const float ero[4] = {cro.x, cro.y, cro.z, cro.w};
                const float eio[4] = {cio.x, cio.y, cio.z, cio.w};
                #pragma unroll
                for (int j = 0; j < 2; j++) {
                    #pragma unroll
                    for (int i = 0; i < 4; i++) {
                        Ter[j][i] += ere[i] * rr[j] - eie[i] * ri[j];
                        Tei[j][i] += ere[i] * ri[j] + eie[i] * rr[j];
                        Tor[j][i] += ero[i] * rr[j] - eio[i] * ri[j];
                        Toi[j][i] += ero[i] * ri[j] + eio[i] * rr[j];
                    }
                    const float nr = rr[j] * wr[j] - ri[j] * wi[j];
                    const float ni = rr[j] * wi[j] + ri[j] * wr[j];
                    rr[j] = nr; ri[j] = ni;
                }
            }
        }
        __syncthreads();   // uniform barrier: ALL E reads done before G' store

        if (act) {
            // radix-2 butterfly + bd/4096 twiddle + store (b <= 32 only)
            float os[2], oc[2];
            #pragma unroll
            for (int j = 0; j < 2; j++)
                fsincos((TWO_PI / 64.0f) * (float)(d0 + j), &os[j], &oc[j]);
            #pragma unroll
            for (int i = 0; i < 4; i++) {
                const int b = b0 + i;
                if (b > 32) continue;
                float gpr[2], gpi[2], gmr[2], gmi[2];
                #pragma unroll
                for (int j = 0; j < 2; j++) {
                    const int d = d0 + j;
                    const float ur = oc[j] * Tor[j][i] - os[j] * Toi[j][i];
                    const float ui = oc[j] * Toi[j][i] + os[j] * Tor[j][i];
                    const float pr = Ter[j][i] + ur, pi = Tei[j][i] + ui;
                    const float mr = Ter[j][i] - ur, mi = Tei[j][i] - ui;
                    float s, c;
                    fsincos((TWO_PI / 4096.0f) * (float)(b * d), &s, &c);
                    gpr[j] = pr * c - pi * s; gpi[j] = pr * s + pi * c;
                    fsincos((TWO_PI / 4096.0f) * (float)(b * (d + 32)), &s, &c);
                    gmr[j] = mr * c - mi * s; gmi[j] = mr * s + mi * c;
                }
                *(float2*)&Gr[b * GS + d0]      = make_float2(gpr[0], gpr[1]);
                *(float2*)&Gi[b * GS + d0]      = make_float2(gpi[0], gpi[1]);
                *(float2*)&Gr[b * GS + d0 + 32] = make_float2(gmr[0], gmr[1]);
                *(float2*)&Gi[b * GS + d0 + 32] = make_float2(gmi[0], gmi[1]);
            }
        }
    }
    __syncthreads();

    // ---------------- stage 2 (R16 rolled loop, 4 groups = b 0..31) -------
    float hv[4][2];
    int   dl_, cg_;
    {
        const int dl = (t & 31) * 2;
        const int cg = t >> 5;                     // 0..7
        dl_ = dl; cg_ = cg;
        float swi_, swr_; fsincos((TWO_PI / 64.0f) * (float)cg, &swi_, &swr_);
        const float swr = swr_, swi = swi_;        // step e^{2pi i cg/64}
        float rr = 1.0f, ri = 0.0f;
        float acc00 = 0, acc01 = 0, acc10 = 0, acc11 = 0;
        float acc20 = 0, acc21 = 0, acc30 = 0, acc31 = 0;
        int bb = 0;

#define S2C 0.70710678118654752f
#define STEP2(f8r, f8i, f16r, f16i, f24r, f24i)                                \
        {                                                                      \
            const float2 g_r = *(const float2*)&Gr[bb * GS + dl];              \
            const float2 g_i = *(const float2*)&Gi[bb * GS + dl];              \
            acc00 += g_r.x * rr - g_i.x * ri;                                  \
            acc01 += g_r.y * rr - g_i.y * ri;                                  \
            { const float tr = rr*(f8r) - ri*(f8i), ti = rr*(f8i) + ri*(f8r);  \
              acc10 += g_r.x * tr - g_i.x * ti;                                \
              acc11 += g_r.y * tr - g_i.y * ti; }                              \
            { const float tr = rr*(f16r) - ri*(f16i), ti = rr*(f16i) + ri*(f16r); \
              acc20 += g_r.x * tr - g_i.x * ti;                                \
              acc21 += g_r.y * tr - g_i.y * ti; }                              \
            { const float tr = rr*(f24r) - ri*(f24i), ti = rr*(f24i) + ri*(f24r); \
              acc30 += g_r.x * tr - g_i.x * ti;                                \
              acc31 += g_r.y * tr - g_i.y * ti; }                              \
            { const float nr = rr * swr - ri * swi;                            \
              const float ni = rr * swi + ri * swr;                            \
              rr = nr; ri = ni; }                                              \
            bb++;                                                              \
        }

        #pragma unroll 1
        for (int grp = 0; grp < 4; grp++) {        // b = 0..31 (rolled!)
            STEP2( 1.0f, 0.0f,   1.0f, 0.0f,   1.0f, 0.0f)
            STEP2( S2C,  S2C,    0.0f, 1.0f,  -S2C,  S2C)
            STEP2( 0.0f, 1.0f,  -1.0f, 0.0f,   0.0f,-1.0f)
            STEP2(-S2C,  S2C,    0.0f,-1.0f,   S2C,  S2C)
            STEP2(-1.0f, 0.0f,   1.0f, 0.0f,  -1.0f, 0.0f)
            STEP2(-S2C, -S2C,    0.0f, 1.0f,   S2C, -S2C)
            STEP2( 0.0f,-1.0f,  -1.0f, 0.0f,   0.0f, 1.0f)
            STEP2( S2C, -S2C,    0.0f,-1.0f,  -S2C, -S2C)
        }
#undef STEP2

        // Hermitian fixup: loop counted b=0 once in every acc; true sum is
        //   g0 + (-1)^cg * g32 + 2 * sum_{b=1..31} = 2*acc - g0 + sgn*g32
        const float g0a  = Gr[dl],           g0b  = Gr[dl + 1];
        const float g32a = Gr[32 * GS + dl], g32b = Gr[32 * GS + dl + 1];
        const float sgn  = (cg & 1) ? -1.0f : 1.0f;   // (-1)^{cg+8v} = (-1)^cg
        const float sc = 1.0f / 4096.0f;
        hv[0][0] = (2.0f * acc00 - g0a + sgn * g32a) * sc;
        hv[0][1] = (2.0f * acc01 - g0b + sgn * g32b) * sc;
        hv[1][0] = (2.0f * acc10 - g0a + sgn * g32a) * sc;
        hv[1][1] = (2.0f * acc11 - g0b + sgn * g32b) * sc;
        hv[2][0] = (2.0f * acc20 - g0a + sgn * g32a) * sc;
        hv[2][1] = (2.0f * acc21 - g0b + sgn * g32b) * sc;
        hv[3][0] = (2.0f * acc30 - g0a + sgn * g32a) * sc;
        hv[3][1] = (2.0f * acc31 - g0b + sgn * g32b) * sc;
    }
    __syncthreads();   // all G reads done; U is free

    // ---------------- h -> LDS ----------------
    #pragma unroll
    for (int v = 0; v < 4; v++) {
        const int c = cg_ + 8 * v;
        const int n = 64 * c + dl_;
        if (n < IR_LEN)     hU[n]     = hv[v][0];
        if (n + 1 < IR_LEN) hU[n + 1] = hv[v][1];
    }
    __syncthreads();

    // ---------------- FIR: z[o], o in [0,160) ----------------
    if (t < 240) {
        const int o0 = (t % 20) * 8;
        const int kc = t / 20;                 // 0..11
        const int kb = kc * 168;
        const int ns = (kc == 11) ? 38 : 42;   // 11*168=1848, +152 = 2000
        float s0[8] = {0,0,0,0,0,0,0,0};
        int Bo = o0 + 1996 - kb;               // mult of 4, >= 0
        float4 w1 = *(const float4*)&xws[XPHYS(Bo + 4)];
        float4 w2 = *(const float4*)&xws[XPHYS(Bo + 8)];
        for (int s = 0; s < ns; s++) {
            const float4 w0 = *(const float4*)&xws[XPHYS(Bo)];
            const float4 ha = *(const float4*)&hU[kb + 4 * s];
            const float wv[12] = {w0.x, w0.y, w0.z, w0.w,
                                  w1.x, w1.y, w1.z, w1.w,
                                  w2.x, w2.y, w2.z, w2.w};
            const float hav[4] = {ha.x, ha.y, ha.z, ha.w};
            #pragma unroll
            for (int jo = 0; jo < 8; jo++) {
                #pragma unroll
                for (int jk = 0; jk < 4; jk++) {
                    s0[jo] += hav[jk] * wv[3 + jo - jk];
                }
            }
            w2 = w1; w1 = w0; Bo -= 4;
        }
        const int rb = kc * 168 + o0;
        *(float4*)&red[rb]     = make_float4(s0[0], s0[1], s0[2], s0[3]);
        *(float4*)&red[rb + 4] = make_float4(s0[4], s0[5], s0[6], s0[7]);
    }
    __syncthreads();

    // ---------------- epilogue: tent-weighted atomic scatter ----------------
    if (t < 160) {
        float z = 0.0f;
        #pragma unroll
        for (int kc = 0; kc < 12; kc++) z += red[kc * 168 + t];
        const int o = t;
        const int tout = t0 - PFRAME + o;
        float wgt = (o < PFRAME) ? (float)o * (1.0f / PFRAME)
                                 : (float)(160 - o) * (1.0f / PFRAME);
        if (frame == NFRAMES - 1 && o >= PFRAME) wgt = 1.0f;  // clamped h_next
        if (tout >= 0) {                       // frame 0 has no previous frame
            atomicAdd(&y[batch * T_TOTAL + tout], wgt * z);
        }
    }
}

extern "C" void kernel_launch(void* const* d_in, const int* in_sizes, int n_in,
                              void* d_out, int out_size, void* d_ws, size_t ws_size,
                              hipStream_t stream) {
    const float* x  = (const float*)d_in[0];   // (2, 24000)
    const float* mc = (const float*)d_in[1];   // (2, 300, 25)
    float* y = (float*)d_out;                  // (2, 24000)

    hipMemsetAsync(y, 0, (size_t)out_size * sizeof(float), stream);
    minphase_fir_fused<<<NROWS, 256, 0, stream>>>(mc, x, y);
}